// Round 1
// 650.426 us; speedup vs baseline: 1.0118x; 1.0118x over previous
//
#include <hip/hip_runtime.h>
#include <math.h>

// Problem constants (match reference):
#define BB    2
#define NN    8192
#define DD    256
#define NBINS 32
#define BINSZ 256
#define NPROJ 16     // n_bins // 2
#define TOPK  16
#define NPTS  (BB * NN)   // 16384

// Fill partition (flat row id = b*NN + point): rows [0,F1) zeroed by k_bins,
// [F1,F2) by k_sort's filler blocks, [F2,NPTS) by k_sim interleaved.
#define FPB 14                 // fill rows per block (256 blocks per kernel)
#define F1  (256 * FPB)        // 3584
#define F2  (2 * 256 * FPB)    // 7168

typedef float vf4 __attribute__((ext_vector_type(4)));

// ---------------------------------------------------------------------------
// K1+fill: wave 0 bins 64 points (numerics identical since R1 — absmax 0.0);
// all 4 waves zero rows [bid*FPB, (bid+1)*FPB) of batch 0.  (unchanged)
// ---------------------------------------------------------------------------
__global__ __launch_bounds__(256) void k_bins_fill(const float* __restrict__ x,
                                                   const float* __restrict__ cb,
                                                   int* __restrict__ bin_idx,
                                                   float* __restrict__ out) {
    __shared__ double cbd[DD][NPROJ];   // 32 KB
    const int t   = threadIdx.x;        // 0..255
    const int bid = blockIdx.x;         // 0..255

    for (int q = t; q < DD * 4; q += 256) {
        int d = q >> 2, j4 = q & 3;
        float4 v = *(const float4*)(cb + d * 32 + j4 * 4);
        cbd[d][j4 * 4 + 0] = (double)v.x;
        cbd[d][j4 * 4 + 1] = (double)v.y;
        cbd[d][j4 * 4 + 2] = (double)v.z;
        cbd[d][j4 * 4 + 3] = (double)v.w;
    }
    __syncthreads();

    // ---- fill first (fire-and-forget; binning compute hides under it) ----
    {
        const vf4 z4 = (vf4)0.0f;
#pragma unroll 1
        for (int q = 0; q < FPB; ++q) {
            vf4* orow = (vf4*)(out + (size_t)(bid * FPB + q) * NN);
#pragma unroll
            for (int j = 0; j < 8; ++j)
                orow[j * 256 + t] = z4;     // 8 x 4 KB per row
        }
    }

    if (t < 64) {
        // ---- binning (wave 0), numerics unchanged ----
        const int p = bid * 64 + t;                // 0..16383
        const float* xr = x + (size_t)p * DD;

        double a[NPROJ];
#pragma unroll
        for (int j = 0; j < NPROJ; ++j) a[j] = 0.0;

        for (int d0 = 0; d0 < DD; d0 += 4) {
            float4 xv = *(const float4*)(xr + d0);
            float xs[4] = {xv.x, xv.y, xv.z, xv.w};
#pragma unroll
            for (int dd = 0; dd < 4; ++dd) {
                double xd = (double)xs[dd];
#pragma unroll
                for (int j = 0; j < NPROJ; ++j)
                    a[j] = fma(cbd[d0 + dd][j], xd, a[j]);
            }
        }

        float bv = -INFINITY; int bj = 0;
#pragma unroll
        for (int j = 0; j < NPROJ; ++j) {
            float m = (float)a[j];
            if (m > bv) { bv = m; bj = j; }
        }
#pragma unroll
        for (int j = 0; j < NPROJ; ++j) {
            float m = -(float)a[j];
            if (m > bv) { bv = m; bj = j + NPROJ; }
        }
        bin_idx[p] = bj;
    }
}

// ---------------------------------------------------------------------------
// K2+fill: grid 258. Blocks 0-1: stable counting sort (unchanged since R1).
// Blocks 2..257: zero rows [F1 + (bid-2)*FPB, +FPB).  (unchanged)
// ---------------------------------------------------------------------------
__global__ __launch_bounds__(256) void k_sort_fill(const int* __restrict__ bin_idx,
                                                   int* __restrict__ order,
                                                   float* __restrict__ out) {
    const int t   = threadIdx.x;
    const int bid = blockIdx.x;

    if (bid >= 2) {
        const vf4 z4 = (vf4)0.0f;
#pragma unroll 1
        for (int q = 0; q < FPB; ++q) {
            vf4* orow = (vf4*)(out + (size_t)(F1 + (bid - 2) * FPB + q) * NN);
#pragma unroll
            for (int j = 0; j < 8; ++j)
                orow[j * 256 + t] = z4;
        }
        return;
    }

    __shared__ int c[NBINS][256];   // 32 KB
    __shared__ int base[NBINS];
    const int b = bid;
    const int* bi = bin_idx + b * NN;

    for (int j = 0; j < NBINS; ++j) c[j][t] = 0;
    __syncthreads();

    const int i0 = t * 32;
    for (int i = 0; i < 32; ++i) c[bi[i0 + i]][t]++;
    __syncthreads();

    if (t < NBINS) {
        int s = 0;
        for (int q = 0; q < 256; ++q) s += c[t][q];
        base[t] = s;
    }
    __syncthreads();
    if (t == 0) {
        int run = 0;
        for (int j = 0; j < NBINS; ++j) { int tmp = base[j]; base[j] = run; run += tmp; }
    }
    __syncthreads();
    if (t < NBINS) {
        int run = base[t];
        for (int q = 0; q < 256; ++q) { int tmp = c[t][q]; c[t][q] = run; run += tmp; }
    }
    __syncthreads();

    int* ob = order + b * NN;
    for (int i = 0; i < 32; ++i) {
        int gi = i0 + i;
        int bb = bi[gi];
        int pos = c[bb][t]++;
        ob[pos] = gi;
    }
}

// ---------------------------------------------------------------------------
// K2.5 (new): gather+transpose the binned points into ptsT[b][bin][d][col]
// so k_sim's B loads are fully coalesced (lane = col).  ~34 MB traffic.
// Grid 256 = 2 batches x 32 bins x 4 column-quads; 64 cols x 256 dims each.
// ---------------------------------------------------------------------------
__global__ __launch_bounds__(256) void k_gather(const float* __restrict__ x,
                                               const int* __restrict__ order,
                                               float* __restrict__ ptsT) {
    __shared__ float tile[64][260];     // 65 KB; stride 260 keeps float4 align
    __shared__ int   idx64[64];
    const int t = threadIdx.x;
    const int g = blockIdx.x;           // 0..255
    const int b    = g >> 7;            // 0..1
    const int bin  = (g >> 2) & 31;     // 0..31
    const int quad = g & 3;             // 0..3
    const int c0   = quad * 64;

    if (t < 64) idx64[t] = order[b * NN + bin * BINSZ + c0 + t];
    __syncthreads();

    // load 64 gathered rows x 256 dims; 4 threads per row, coalesced in-row
    {
        const int col  = t >> 2;        // 0..63
        const int part = t & 3;         // 0..3
        const float* xr = x + ((size_t)b * NN + idx64[col]) * DD;
#pragma unroll
        for (int q = 0; q < 16; ++q) {
            float4 v = *(const float4*)(xr + (part + 4 * q) * 4);
            *(float4*)&tile[col][(part + 4 * q) * 4] = v;
        }
    }
    __syncthreads();

    // transposed write-out: per pass 4 dims, lanes -> consecutive cols
    const int cc   = t & 63;
    const int dsub = t >> 6;            // 0..3
    float* op = ptsT + (size_t)(b * NBINS + bin) * DD * BINSZ;
#pragma unroll 4
    for (int dp = 0; dp < 64; ++dp) {
        const int d = dp * 4 + dsub;
        op[(size_t)d * BINSZ + c0 + cc] = tile[cc][d];  // 256 B/instr, coalesced
    }
}

// ---------------------------------------------------------------------------
// K3: same structure as before EXCEPT the B operand now streams from ptsT
// (dim-major) with fully-coalesced dwordx4 loads: lane owns cols 4c..4c+3.
// Per-output fp64 FMA order over ascending d is IDENTICAL -> absmax 0.0.
// XCD swizzle: all 8 row-blocks of one (b,bin) land on one XCD's L2.
// ---------------------------------------------------------------------------
#define RT 32
__global__ __launch_bounds__(256, 2) void k_sim(const float* __restrict__ x,
                                                const int* __restrict__ order,
                                                const float* __restrict__ ptsT,
                                                float* __restrict__ out) {
    __shared__ int   idx[BINSZ];            // 1 KB
    __shared__ float As[RT][260];           // 33.3 KB
    __shared__ float S[RT][BINSZ + 1];      // ~32.9 KB
    __shared__ float tvs[RT][TOPK];         // 2 KB
    __shared__ int   tds[RT][TOPK];         // 2 KB

    const int t   = threadIdx.x;             // 0..255
    const int bid = blockIdx.x;              // 0..511
    // XCD-aware remap (bijective): xcd = bid&7; 8 bins per xcd; 8 sub-blocks/bin
    const int cx  = bid & 7;
    const int rr_ = bid >> 3;                // 0..63
    const int bl  = cx * 8 + (rr_ & 7);      // 0..63  (= b*32+bin)
    const int b   = bl >> 5;
    const int bin = bl & 31;
    const int r0  = (rr_ >> 3) * RT;

    idx[t] = order[b * NN + bin * BINSZ + t];
    __syncthreads();

    const float* xb = x + (size_t)b * NN * DD;
    const float* bT = ptsT + (size_t)(b * NBINS + bin) * DD * BINSZ;

    // ---- stage A rows r0..r0+31 (all 256 dims) into LDS, coalesced ----
    {
        const int ar = t >> 3;               // 0..31
        const int ac = t & 7;                // 0..7
        const float* ag = xb + (size_t)idx[r0 + ar] * DD;
#pragma unroll
        for (int q = 0; q < 8; ++q) {
            float4 v = *(const float4*)(ag + (ac + 8 * q) * 4);
            *(float4*)&As[ar][(ac + 8 * q) * 4] = v;
        }
    }

    // compute assignment: rows rg*8..rg*8+7 (block-local), cols 4*cbase..+3
    const int rg    = t >> 6;                // wave id -> A reads wave-uniform
    const int cbase = t & 63;

    double acc[8][4];
#pragma unroll
    for (int r = 0; r < 8; ++r)
#pragma unroll
        for (int k = 0; k < 4; ++k) acc[r][k] = 0.0;

    const vf4 z4 = (vf4)0.0f;

    __syncthreads();   // A-tile ready. Only barrier before the epilogue.

#pragma unroll 1
    for (int it = 0; it < 16; ++it) {
        const int k0 = it * 16;

        // ---- B loads FIRST (older than this iter's stores): 16 dims x 4 cols,
        //      lane-contiguous 16 B -> 1 KB coalesced per instruction ----
        float4 bv[16];
#pragma unroll
        for (int dq = 0; dq < 16; ++dq)
            bv[dq] = *(const float4*)(bT + (size_t)(k0 + dq) * BINSZ + 4 * cbase);

        // ---- zero up to 2 rows (skip rows pre-filled by earlier kernels) ----
        {
            const int zr = it * 2;
#pragma unroll
            for (int rr = 0; rr < 2; ++rr) {
                const int pid = idx[r0 + zr + rr];
                if (b * NN + pid >= F2) {    // wave-uniform guard
                    vf4* orow = (vf4*)(out + ((size_t)b * NN + pid) * NN);
#pragma unroll
                    for (int j = 0; j < 8; ++j)
                        __builtin_nontemporal_store(z4, orow + j * 256 + t);
                }
            }
        }

        // ---- FMA: 8 rows x 4 cols, dims strictly ascending (order preserved) ----
#pragma unroll
        for (int dd4 = 0; dd4 < 4; ++dd4) {
            float4 af[8];
#pragma unroll
            for (int rr = 0; rr < 8; ++rr)   // wave-uniform -> LDS broadcast
                af[rr] = *(const float4*)&As[rg * 8 + rr][k0 + dd4 * 4];
#pragma unroll
            for (int e = 0; e < 4; ++e) {
                const float4 bq = bv[dd4 * 4 + e];   // dim d = k0+dd4*4+e, 4 cols
                const double be0 = (double)bq.x;
                const double be1 = (double)bq.y;
                const double be2 = (double)bq.z;
                const double be3 = (double)bq.w;
#pragma unroll
                for (int rr = 0; rr < 8; ++rr) {
                    const float ae = (e == 0) ? af[rr].x : (e == 1) ? af[rr].y
                                   : (e == 2) ? af[rr].z : af[rr].w;
                    const double ad = (double)ae;
                    acc[rr][0] = fma(ad, be0, acc[rr][0]);
                    acc[rr][1] = fma(ad, be1, acc[rr][1]);
                    acc[rr][2] = fma(ad, be2, acc[rr][2]);
                    acc[rr][3] = fma(ad, be3, acc[rr][3]);
                }
            }
        }
    }

    // ---- sigmoid (reference fp32 chain) -> S; lane owns cols 4*cbase..+3 ----
#pragma unroll
    for (int rr = 0; rr < 8; ++rr)
#pragma unroll
        for (int k = 0; k < 4; ++k) {
            float s32 = (float)acc[rr][k];
            S[rg * 8 + rr][4 * cbase + k] = 1.0f / (1.0f + expf(-s32));
        }
    __syncthreads();   // per-wave vmcnt(0) also drains this wave's zero stores

    // ---- top-16 per row (desc value, ties -> lowest index) ----
    if (t < RT) {
        float tv[TOPK]; int ti[TOPK];
#pragma unroll
        for (int q = 0; q < TOPK; ++q) { tv[q] = -INFINITY; ti[q] = 0; }
        for (int cc = 0; cc < BINSZ; ++cc) {
            float v = S[t][cc];
            if (v > tv[TOPK - 1]) {
                tv[TOPK - 1] = v; ti[TOPK - 1] = cc;
#pragma unroll
                for (int q = TOPK - 1; q > 0; --q) {
                    if (tv[q] > tv[q - 1]) {
                        float fv = tv[q]; tv[q] = tv[q - 1]; tv[q - 1] = fv;
                        int   fi = ti[q]; ti[q] = ti[q - 1]; ti[q - 1] = fi;
                    }
                }
            }
        }
#pragma unroll
        for (int q = 0; q < TOPK; ++q) {
            tvs[t][q] = tv[q];
            tds[t][q] = idx[ti[q]];
        }
    }
    __syncthreads();   // tvs/tds visible; all zero stores fully drained

    // ---- scatter 512 values into the zeroed rows ----
    for (int p = t; p < RT * TOPK; p += 256) {
        int r = p >> 4, q = p & 15;
        float* orow = out + ((size_t)b * NN + idx[r0 + r]) * NN;
        orow[tds[r][q]] = tvs[r][q];
    }
}

// ---------------------------------------------------------------------------
extern "C" void kernel_launch(void* const* d_in, const int* in_sizes, int n_in,
                              void* d_out, int out_size, void* d_ws, size_t ws_size,
                              hipStream_t stream) {
    const float* x  = (const float*)d_in[0];
    const float* cb = (const float*)d_in[1];
    float* out      = (float*)d_out;

    int* bin_idx = (int*)d_ws;           // NPTS ints
    int* order   = bin_idx + NPTS;       // NPTS ints
    float* ptsT  = (float*)(order + NPTS);   // 2*32*256*256 floats = 16.8 MB

    k_bins_fill<<<256, 256, 0, stream>>>(x, cb, bin_idx, out);
    k_sort_fill<<<258, 256, 0, stream>>>(bin_idx, order, out);
    k_gather<<<256, 256, 0, stream>>>(x, order, ptsT);
    k_sim<<<BB * NBINS * 8, 256, 0, stream>>>(x, order, ptsT, out);
}